// Round 4
// baseline (188.920 us; speedup 1.0000x reference)
//
#include <hip/hip_runtime.h>

#define N_ROWS 8192
#define DIM    512

typedef __attribute__((ext_vector_type(4))) float frag_cd;      // 4 fp32 acc
typedef __attribute__((ext_vector_type(4))) int   v4i;          // 16B
typedef __attribute__((ext_vector_type(8))) int   v8i;          // 32B MX A/B fragment

// fp32 -> OCP e4m3fn, RNE, FTZ below 2^-6 (negligible for N(0,1) data).
__device__ __forceinline__ unsigned f2fp8(float x) {
    float a = fabsf(x);
    unsigned s = (__float_as_uint(x) >> 31) << 7;
    if (a < 0.015625f) return s;                 // FTZ subnormals
    a = fminf(a, 448.f);                         // e4m3fn max
    unsigned u = __float_as_uint(a);
    u += 0x7FFFFu + ((u >> 20) & 1u);            // RNE round mantissa to 3 bits
    unsigned exp = (u >> 23) - 120u;             // fp32exp-127+7 in [1,15]
    unsigned mant = (u >> 20) & 7u;
    return s | (exp << 3) | mant;
}
__device__ __forceinline__ unsigned pack4fp8(float4 v) {
    return f2fp8(v.x) | (f2fp8(v.y) << 8) | (f2fp8(v.z) << 16) | (f2fp8(v.w) << 24);
}
// order-preserving f32 -> u32 key (monotone), so atomicMax(uint) == float max
__device__ __forceinline__ unsigned enc_f32(float f) {
    unsigned u = __float_as_uint(f);
    return (u & 0x80000000u) ? ~u : (u | 0x80000000u);
}
__device__ __forceinline__ float dec_f32(unsigned k) {
    return __uint_as_float((k & 0x80000000u) ? (k & 0x7FFFFFFFu) : ~k);
}

// ---- TILED fp8 layout for mfma_scale 16x16x128 (round-2/3 verified exact) ----
// Chunk (cr, kp2) = 16 rows x 128 K-cols = 2 KB at byte cr*8192 + kp2*2048.
// 16B unit index u (0..511 per cr-chunk) is LINEAR: byte off = u*16, with
//   u = kp2*128 + h*64 + q*16 + rin  ->  row rin, K = kp2*128+q*32+h*16+[0..15]
// Consumer lane l reads lo at lane*16, hi at +1024: contiguous per wave.

// ---- kernel 1: convert + diag + init -- COALESCED 16B-unit stores ----
// Thread t of block cr owns units u=t and u=t+256 (same rin/h/q, kp2 and
// kp2+2): gathers 16 K-floats per unit per matrix, packs, stores uint4 at
// linear offset t*16 / t*16+4096 -> perfectly coalesced. Diag via 4-lane
// shfl groups (lanes l, l^16, l^32, l^48 share row rin) + LDS cross-wave.
__global__ __launch_bounds__(256) void k_prep(const float* __restrict__ imgs,
                                              const float* __restrict__ caps,
                                              unsigned char* __restrict__ fimgs,
                                              unsigned char* __restrict__ fcaps,
                                              float* __restrict__ diag,
                                              unsigned* __restrict__ rowmax,
                                              unsigned* __restrict__ colmax,
                                              float* __restrict__ out) {
    const int cr = blockIdx.x;            // 0..511
    const int t  = threadIdx.x;           // 0..255
    if (cr == 0 && t == 0) out[0] = 0.f;  // zero accumulator for k_final
    const int rin = t & 15;
    const int q   = (t >> 4) & 3;
    const int h   = (t >> 6) & 1;
    const int kp2 = t >> 7;               // 0..1 (second unit adds +2)
    const int row = cr * 16 + rin;
    const int kc1 = kp2 * 128 + q * 32 + h * 16;
    const int kc2 = kc1 + 256;
    const float* ai = imgs + (size_t)row * DIM;
    const float* bi = caps + (size_t)row * DIM;
    float4 a[8], b[8];
    #pragma unroll
    for (int j = 0; j < 4; ++j) {
        a[j]     = *(const float4*)(ai + kc1 + 4 * j);
        a[4 + j] = *(const float4*)(ai + kc2 + 4 * j);
        b[j]     = *(const float4*)(bi + kc1 + 4 * j);
        b[4 + j] = *(const float4*)(bi + kc2 + 4 * j);
    }
    uint4 oa1 = make_uint4(pack4fp8(a[0]), pack4fp8(a[1]), pack4fp8(a[2]), pack4fp8(a[3]));
    uint4 oa2 = make_uint4(pack4fp8(a[4]), pack4fp8(a[5]), pack4fp8(a[6]), pack4fp8(a[7]));
    uint4 ob1 = make_uint4(pack4fp8(b[0]), pack4fp8(b[1]), pack4fp8(b[2]), pack4fp8(b[3]));
    uint4 ob2 = make_uint4(pack4fp8(b[4]), pack4fp8(b[5]), pack4fp8(b[6]), pack4fp8(b[7]));
    unsigned char* fA = fimgs + (size_t)cr * 8192 + t * 16;
    unsigned char* fB = fcaps + (size_t)cr * 8192 + t * 16;
    *(uint4*)fA = oa1; *(uint4*)(fA + 4096) = oa2;
    *(uint4*)fB = ob1; *(uint4*)(fB + 4096) = ob2;
    float s = 0.f;
    #pragma unroll
    for (int j = 0; j < 8; ++j)
        s += a[j].x * b[j].x + a[j].y * b[j].y + a[j].z * b[j].z + a[j].w * b[j].w;
    s += __shfl_xor(s, 16, 64);
    s += __shfl_xor(s, 32, 64);           // 4-lane group sum (same rin)
    __shared__ float red[4][16];
    if ((t & 63) < 16) red[t >> 6][rin] = s;
    __syncthreads();
    if (t < 16) {
        diag[cr * 16 + t] = red[0][t] + red[1][t] + red[2][t] + red[3][t];
        rowmax[cr * 16 + t] = 0u;
        colmax[cr * 16 + t] = 0u;
    }
}

// ---- kernel 2: barrier-free direct-to-register MX-fp8 NT-GEMM,
//      now with explicit double-buffered fragment prefetch ----
// Round-3 diagnosis: VGPR=128 = acc(64)+one fragment set(64) -> compiler
// had no room to prefetch; every K-step stalled on L2 latency (MfmaUtil 12%).
// Fix: two named fragment sets (static indices after full unroll), next
// K-step's 16 loads issued BEFORE current MFMA block; no min-waves bound so
// ~210 VGPR (2 waves/SIMD) is allowed. Epilogue verified rounds 2-3.
__global__ __launch_bounds__(256) void k_gemm(const unsigned char* __restrict__ A,
                                              const unsigned char* __restrict__ B,
                                              unsigned* __restrict__ rowmax,
                                              unsigned* __restrict__ colmax) {
    const int tid = threadIdx.x;
    const int w = tid >> 6, lane = tid & 63;
    // XCD-aware swizzle: xcd = f&7 owns jb in {8x..8x+7} (512 KB B-panel);
    // 8 consecutive same-xcd jobs share one A-panel. Heuristic only.
    const int f = (int)blockIdx.x;                 // 0..4095
    const int jb = (f & 7) * 8 + ((f >> 3) & 7);   // 0..63 (128-col panel)
    const int ib = f >> 6;                          // 0..63 (128-row panel)
    const int j0 = jb << 7, i0 = ib << 7;
    const int q = lane >> 4, l15 = lane & 15;
    const int wr = (w & 1) << 6, wc = (w >> 1) << 6;   // wave tile origin in block

    const unsigned char* Ab = A + (size_t)((i0 >> 4) + ((w & 1) << 2)) * 8192 + lane * 16;
    const unsigned char* Bb = B + (size_t)((j0 >> 4) + ((w >> 1) << 2)) * 8192 + lane * 16;

    frag_cd acc[4][4] = {};

    union U { v8i v; struct { v4i lo, hi; } s; };
    U af[2][4], bf[2][4];

    #pragma unroll
    for (int r = 0; r < 4; ++r) {
        af[0][r].s.lo = *(const v4i*)(Ab + (size_t)r * 8192);
        af[0][r].s.hi = *(const v4i*)(Ab + (size_t)r * 8192 + 1024);
        bf[0][r].s.lo = *(const v4i*)(Bb + (size_t)r * 8192);
        bf[0][r].s.hi = *(const v4i*)(Bb + (size_t)r * 8192 + 1024);
    }

    #pragma unroll
    for (int kp2 = 0; kp2 < 4; ++kp2) {
        const int cur = kp2 & 1, nxt = cur ^ 1;   // compile-time after unroll
        if (kp2 < 3) {
            #pragma unroll
            for (int r = 0; r < 4; ++r) {
                af[nxt][r].s.lo = *(const v4i*)(Ab + (size_t)r * 8192 + (kp2 + 1) * 2048);
                af[nxt][r].s.hi = *(const v4i*)(Ab + (size_t)r * 8192 + (kp2 + 1) * 2048 + 1024);
                bf[nxt][r].s.lo = *(const v4i*)(Bb + (size_t)r * 8192 + (kp2 + 1) * 2048);
                bf[nxt][r].s.hi = *(const v4i*)(Bb + (size_t)r * 8192 + (kp2 + 1) * 2048 + 1024);
            }
        }
        #pragma unroll
        for (int r = 0; r < 4; ++r)
            #pragma unroll
            for (int c = 0; c < 4; ++c)
                // fp8(e4m3) x fp8, per-block e8m0 scales all = 127 (=2^0 exact)
                acc[r][c] = __builtin_amdgcn_mfma_scale_f32_16x16x128_f8f6f4(
                    af[cur][r].v, bf[cur][c].v, acc[r][c], 0, 0,
                    0, 0x7F7F7F7F, 0, 0x7F7F7F7F);
    }

    // ---- epilogue: diagonal flip + row/col max + device atomics ----
    // C/D layout (16x16 family): col = lane&15, row = (lane>>4)*4 + reg
    const bool dblk = (i0 == j0);
    #pragma unroll
    for (int r = 0; r < 4; ++r)
        #pragma unroll
        for (int c = 0; c < 4; ++c)
            #pragma unroll
            for (int g = 0; g < 4; ++g) {
                float fv = acc[r][c][g];
                const int gi = wr + (r << 4) + (q << 2) + g;          // row in block
                const int gj = wc + (c << 4) + l15;                   // col in block
                if (dblk && (i0 + gi) == (j0 + gj)) fv = -fv;         // s[i][i] = -diag
                acc[r][c][g] = fv;
            }

    #pragma unroll
    for (int r = 0; r < 4; ++r)
        #pragma unroll
        for (int g = 0; g < 4; ++g) {
            float m = fmaxf(fmaxf(acc[r][0][g], acc[r][1][g]),
                            fmaxf(acc[r][2][g], acc[r][3][g]));
            m = fmaxf(m, __shfl_xor(m, 1, 64));
            m = fmaxf(m, __shfl_xor(m, 2, 64));
            m = fmaxf(m, __shfl_xor(m, 4, 64));
            m = fmaxf(m, __shfl_xor(m, 8, 64));
            if (l15 == 0)
                atomicMax(&rowmax[i0 + wr + (r << 4) + (q << 2) + g], enc_f32(m));
        }
    #pragma unroll
    for (int c = 0; c < 4; ++c) {
        float m = acc[0][c][0];
        #pragma unroll
        for (int r = 0; r < 4; ++r)
            #pragma unroll
            for (int g = 0; g < 4; ++g) m = fmaxf(m, acc[r][c][g]);
        m = fmaxf(m, __shfl_xor(m, 16, 64));
        m = fmaxf(m, __shfl_xor(m, 32, 64));
        if (q == 0)
            atomicMax(&colmax[j0 + wc + (c << 4) + l15], enc_f32(m));
    }
}

// ---- kernel 3: hinge terms, 32 blocks + one atomicAdd per block ----
__global__ __launch_bounds__(256) void k_final(const unsigned* __restrict__ rowmax,
                                               const unsigned* __restrict__ colmax,
                                               const float* __restrict__ diag,
                                               float* __restrict__ out) {
    const int idx = blockIdx.x * 256 + threadIdx.x;
    const float d = diag[idx];
    float s = fmaxf(dec_f32(rowmax[idx]) + 0.2f - d, 0.f)    // neg_img
            + fmaxf(dec_f32(colmax[idx]) + 0.2f - d, 0.f);   // neg_cap
    #pragma unroll
    for (int m = 1; m < 64; m <<= 1) s += __shfl_xor(s, m, 64);
    __shared__ float red[4];
    if ((threadIdx.x & 63) == 0) red[threadIdx.x >> 6] = s;
    __syncthreads();
    if (threadIdx.x == 0)
        atomicAdd(out, red[0] + red[1] + red[2] + red[3]);
}

extern "C" void kernel_launch(void* const* d_in, const int* in_sizes, int n_in,
                              void* d_out, int out_size, void* d_ws, size_t ws_size,
                              hipStream_t stream) {
    const float* imgs = (const float*)d_in[0];
    const float* caps = (const float*)d_in[1];
    float* out = (float*)d_out;

    char* ws = (char*)d_ws;
    unsigned char* fimgs = (unsigned char*)ws;                         // 4 MB tiled fp8
    unsigned char* fcaps = (unsigned char*)(ws + 4194304);             // 4 MB tiled fp8
    float*    diag   = (float*)   (ws + 8388608);                      // 32 KB
    unsigned* rowmax = (unsigned*)(ws + 8388608 + 32768);              // 32 KB
    unsigned* colmax = (unsigned*)(ws + 8388608 + 65536);              // 32 KB

    k_prep<<<512, 256, 0, stream>>>(imgs, caps, fimgs, fcaps,
                                    diag, rowmax, colmax, out);
    k_gemm<<<4096, 256, 0, stream>>>(fimgs, fcaps, rowmax, colmax);
    k_final<<<N_ROWS / 256, 256, 0, stream>>>(rowmax, colmax, diag, out);
}